// Round 1
// baseline (53.073 us; speedup 1.0000x reference)
//
#include <hip/hip_runtime.h>
#include <math.h>

#define MGT   64
#define NANCH 211200
#define PI_F  3.14159265358979323846f

// Axis-aligned 3D IoU, written in EXACTLY the numpy reference's op order.
// All contraction-sensitive spots are benign (x*0.5 is exact under FMA),
// so plain IEEE float ops reproduce numpy bit-for-bit.
static __device__ __forceinline__ float iou_one(
    const float glo0, const float glo1, const float glo2,
    const float ghi0, const float ghi1, const float ghi2, const float volg,
    const float alo0, const float alo1, const float alo2,
    const float ahi0, const float ahi1, const float ahi2, const float vola)
{
    float ov0 = fminf(ghi0, ahi0) - fmaxf(glo0, alo0);  ov0 = fmaxf(ov0, 0.0f);
    float ov1 = fminf(ghi1, ahi1) - fmaxf(glo1, alo1);  ov1 = fmaxf(ov1, 0.0f);
    float ov2 = fminf(ghi2, ahi2) - fmaxf(glo2, alo2);  ov2 = fmaxf(ov2, 0.0f);
    const float inter = (ov0 * ov1) * ov2;
    float iou = 0.0f;
    if (inter > 0.0f)   // skip IEEE-div sequence for the ~99.7% empty pairs
        iou = inter / ((volg + vola) - inter);
    return iou;
}

// Pass A: gt_best[g] = max over all anchors of iou(g, a).
// IoU >= 0, so float-as-int atomicMax is order-preserving; d_ws pre-zeroed.
__global__ __launch_bounds__(256) void gt_best_kernel(
    const float* __restrict__ gt, const float* __restrict__ anch,
    int* __restrict__ gbest_bits)
{
    __shared__ float s_glo[MGT][3], s_ghi[MGT][3], s_vol[MGT];
    __shared__ int   s_max[MGT];
    const int t = threadIdx.x;
    if (t < MGT) {
        const float cx = gt[t*7+0], cy = gt[t*7+1], cz = gt[t*7+2];
        const float w  = gt[t*7+3], l  = gt[t*7+4], h  = gt[t*7+5];
        s_glo[t][0] = cx - w*0.5f;  s_ghi[t][0] = cx + w*0.5f;
        s_glo[t][1] = cy - l*0.5f;  s_ghi[t][1] = cy + l*0.5f;
        s_glo[t][2] = cz - h*0.5f;  s_ghi[t][2] = cz + h*0.5f;
        s_vol[t] = (w*l)*h;
        s_max[t] = 0;
    }
    __syncthreads();

    const int i = blockIdx.x*256 + t;
    if (i < NANCH) {
        const float ax = anch[i*7+0], ay = anch[i*7+1], az = anch[i*7+2];
        const float aw = anch[i*7+3], al = anch[i*7+4], ah = anch[i*7+5];
        const float alo0 = ax - aw*0.5f, ahi0 = ax + aw*0.5f;
        const float alo1 = ay - al*0.5f, ahi1 = ay + al*0.5f;
        const float alo2 = az - ah*0.5f, ahi2 = az + ah*0.5f;
        const float vola = (aw*al)*ah;
        for (int g = 0; g < MGT; ++g) {
            const float iou = iou_one(s_glo[g][0], s_glo[g][1], s_glo[g][2],
                                      s_ghi[g][0], s_ghi[g][1], s_ghi[g][2], s_vol[g],
                                      alo0, alo1, alo2, ahi0, ahi1, ahi2, vola);
            const int bits = __float_as_int(iou);
            // monotone LDS value: a stale (smaller) read never skips a needed update
            if (bits > s_max[g]) atomicMax(&s_max[g], bits);
        }
    }
    __syncthreads();
    if (t < MGT) atomicMax(&gbest_bits[t], s_max[t]);
}

// Pass B: per anchor -> argmax (first-index), labels (thresholds + rescue
// equality vs gt_best), VoxelNet delta encode. Writes all outputs.
__global__ __launch_bounds__(256) void assign_kernel(
    const float* __restrict__ gt, const float* __restrict__ anch,
    const int* __restrict__ gbest_bits, float* __restrict__ out)
{
    __shared__ float s_gt[MGT][7];
    __shared__ float s_glo[MGT][3], s_ghi[MGT][3], s_vol[MGT], s_best[MGT];
    const int t = threadIdx.x;
    if (t < MGT) {
        const float cx = gt[t*7+0], cy = gt[t*7+1], cz = gt[t*7+2];
        const float w  = gt[t*7+3], l  = gt[t*7+4], h  = gt[t*7+5];
        s_glo[t][0] = cx - w*0.5f;  s_ghi[t][0] = cx + w*0.5f;
        s_glo[t][1] = cy - l*0.5f;  s_ghi[t][1] = cy + l*0.5f;
        s_glo[t][2] = cz - h*0.5f;  s_ghi[t][2] = cz + h*0.5f;
        s_vol[t]  = (w*l)*h;
        s_best[t] = __int_as_float(gbest_bits[t]);
    }
    for (int j = t; j < MGT*7; j += 256) ((float*)s_gt)[j] = gt[j];
    __syncthreads();

    const int i = blockIdx.x*256 + t;
    if (i >= NANCH) return;

    const float ax = anch[i*7+0], ay = anch[i*7+1], az = anch[i*7+2];
    const float aw = anch[i*7+3], al = anch[i*7+4], ah = anch[i*7+5];
    const float ayaw = anch[i*7+6];
    const float alo0 = ax - aw*0.5f, ahi0 = ax + aw*0.5f;
    const float alo1 = ay - al*0.5f, ahi1 = ay + al*0.5f;
    const float alo2 = az - ah*0.5f, ahi2 = az + ah*0.5f;
    const float vola = (aw*al)*ah;

    float best = -1.0f;       // strict > keeps FIRST max index (numpy argmax)
    int   bi = 0;
    bool  rescue = false;
    for (int g = 0; g < MGT; ++g) {
        const float iou = iou_one(s_glo[g][0], s_glo[g][1], s_glo[g][2],
                                  s_ghi[g][0], s_ghi[g][1], s_ghi[g][2], s_vol[g],
                                  alo0, alo1, alo2, ahi0, ahi1, ahi2, vola);
        if (iou > best) { best = iou; bi = g; }
        rescue = rescue | (iou == s_best[g]);
    }

    const float label = rescue ? 1.0f
                      : (best >= 0.5f ? 1.0f : (best >= 0.35f ? -1.0f : 0.0f));

    const float gx = s_gt[bi][0], gy = s_gt[bi][1], gz = s_gt[bi][2];
    const float gw = s_gt[bi][3], gl = s_gt[bi][4], gh = s_gt[bi][5];
    const float gyaw = s_gt[bi][6];

    const float diag = sqrtf(aw*aw + al*al);
    float d7[7];
    d7[0] = (gx - ax) / diag;
    d7[1] = (gy - ay) / diag;
    d7[2] = (gz - az) / ah;
    d7[3] = logf(gw / aw);
    d7[4] = logf(gl / al);
    d7[5] = logf(gh / ah);
    float dy = gyaw - ayaw;
    float r  = fmodf(dy, PI_F);
    if (r < 0.0f) r += PI_F;   // numpy-mod semantics (sign of divisor)
    d7[6] = r;

    #pragma unroll
    for (int k = 0; k < 7; ++k) out[i*7 + k] = d7[k];
    out[NANCH*7 + i]         = (float)bi;
    out[NANCH*7 + NANCH + i] = label;
}

extern "C" void kernel_launch(void* const* d_in, const int* in_sizes, int n_in,
                              void* d_out, int out_size, void* d_ws, size_t ws_size,
                              hipStream_t stream)
{
    // defensive input-order resolution via sizes (gt = 64*7 = 448 elements)
    const float* gt   = (const float*)d_in[0];
    const float* anch = (const float*)d_in[1];
    if (in_sizes[0] != MGT*7) { gt = (const float*)d_in[1]; anch = (const float*)d_in[0]; }

    float* out   = (float*)d_out;
    int*   gbest = (int*)d_ws;

    hipMemsetAsync(gbest, 0, MGT*sizeof(int), stream);  // graph-capturable
    const int grid = (NANCH + 255) / 256;
    gt_best_kernel<<<grid, 256, 0, stream>>>(gt, anch, gbest);
    assign_kernel <<<grid, 256, 0, stream>>>(gt, anch, gbest, out);
}

// Round 3
// 39.615 us; speedup vs baseline: 1.3397x; 1.3397x over previous
//
#include <hip/hip_runtime.h>
#include <math.h>

#define MGT   64
#define NXg   200
#define NYg   176
#define NANCH (NXg*NYg*2*3)     // 211200
#define TX    8
#define TY    16
#define PI_F  3.14159265358979323846f

// strides (in floats) within the flat anchors (N,7) array
#define AX_STRIDE (NYg*2*3*7)   // 7392 between consecutive x indices
#define AY_STRIDE (2*3*7)       // 42 between consecutive y indices

// One kernel body, two passes over the SAME per-pair iou values (identical
// code path -> identical bits):
//   PASS 0: gt_best[g] = max over anchors of iou(g,a), via LDS+global
//           atomicMax on float bits (iou >= 0 so int order == value order).
//   PASS 1: per-anchor argmax (first-index), labels (thresholds + rescue
//           *exact equality* vs gt_best), VoxelNet delta encode.
// gt_best computed from exactly the values PASS 1 compares against makes the
// rescue test robust by construction (R2's closed-form max broke this).
template<int PASS>
__global__ __launch_bounds__(128) void tile_kernel(
    const float* __restrict__ gt, const float* __restrict__ anch,
    int* __restrict__ gbest_bits, float* __restrict__ out)
{
    __shared__ float  s_gt[MGT][7];
    __shared__ float  s_lo[3][MGT], s_hi[3][MGT];
    __shared__ float  s_volg[MGT];
    __shared__ float  s_ovx[TX][MGT+1];   // +1 pad: row stride hits distinct banks
    __shared__ float  s_ovy[TY][MGT+1];
    __shared__ float4 s_gc[MGT];          // (ovz, volg+vola, gt_best, 0)
    __shared__ float  s_xc[TX], s_yc[TY];
    __shared__ float  s_cls[6];           // w, l, h, z, yaw0, yaw1
    __shared__ int    s_max[MGT];         // PASS 0 block-local max (iou bits)

    const int t  = threadIdx.x;
    const int c  = blockIdx.z;
    const int x0 = blockIdx.x * TX, y0 = blockIdx.y * TY;

    // ---- phase 1: gt rows + bounds, anchor tile centers, class consts
    if (t < MGT) {
        float v[7];
        #pragma unroll
        for (int k = 0; k < 7; ++k) { v[k] = gt[t*7+k]; s_gt[t][k] = v[k]; }
        s_lo[0][t] = v[0] - v[3]*0.5f;  s_hi[0][t] = v[0] + v[3]*0.5f;
        s_lo[1][t] = v[1] - v[4]*0.5f;  s_hi[1][t] = v[1] + v[4]*0.5f;
        s_lo[2][t] = v[2] - v[5]*0.5f;  s_hi[2][t] = v[2] + v[5]*0.5f;
        s_volg[t]  = (v[3]*v[4])*v[5];
        s_max[t]   = 0;
    } else if (t < MGT + TX) {
        s_xc[t - MGT] = anch[(size_t)(x0 + t - MGT) * AX_STRIDE];
    } else if (t < MGT + TX + TY) {
        s_yc[t - MGT - TX] = anch[(size_t)(y0 + t - MGT - TX) * AY_STRIDE + 1];
    } else if (t == MGT + TX + TY) {
        s_cls[0] = anch[c*7+3];   // w
        s_cls[1] = anch[c*7+4];   // l
        s_cls[2] = anch[c*7+5];   // h
        s_cls[3] = anch[c*7+2];   // z
        s_cls[4] = anch[6];       // yaw value 0
        s_cls[5] = anch[3*7+6];   // yaw value 1
    }
    __syncthreads();

    // ---- phase 2: per-axis overlap tables for this tile/class
    const float w = s_cls[0], l = s_cls[1], h = s_cls[2], zc = s_cls[3];
    for (int idx = t; idx < TX*MGT; idx += 128) {
        const int xi = idx >> 6, g = idx & 63;
        const float ax = s_xc[xi];
        s_ovx[xi][g] = fmaxf(fminf(s_hi[0][g], ax + w*0.5f) - fmaxf(s_lo[0][g], ax - w*0.5f), 0.0f);
    }
    for (int idx = t; idx < TY*MGT; idx += 128) {
        const int yi = idx >> 6, g = idx & 63;
        const float ay = s_yc[yi];
        s_ovy[yi][g] = fmaxf(fminf(s_hi[1][g], ay + l*0.5f) - fmaxf(s_lo[1][g], ay - l*0.5f), 0.0f);
    }
    if (t < MGT) {
        const float ovz = fmaxf(fminf(s_hi[2][t], zc + h*0.5f) - fmaxf(s_lo[2][t], zc - h*0.5f), 0.0f);
        const float vola = (w*l)*h;
        const float gb = (PASS == 1) ? __int_as_float(gbest_bits[t]) : 0.0f;
        s_gc[t] = make_float4(ovz, s_volg[t] + vola, gb, 0.0f);
    }
    __syncthreads();

    // ---- main loop over 64 gt rows
    const int lx = t >> 4, ly = t & 15;
    const float* __restrict__ povx = &s_ovx[lx][0];
    const float* __restrict__ povy = &s_ovy[ly][0];
    float best = -1.0f;   // strict > keeps FIRST max index (numpy argmax)
    int   bi = 0;
    bool  rescue = false;
    #pragma unroll 8
    for (int g = 0; g < MGT; ++g) {
        const float  ovxv = povx[g];
        const float  ovyv = povy[g];
        const float4 gc   = s_gc[g];
        const float  inter = (ovxv * ovyv) * gc.x;   // same order as numpy
        float iou = 0.0f;
        if (inter > 0.0f)                  // skip IEEE-div for empty pairs
            iou = inter / (gc.y - inter);
        if (PASS == 0) {
            const int bits = __float_as_int(iou);
            // monotone LDS value: a stale (smaller) read never skips an update
            if (bits > s_max[g]) atomicMax(&s_max[g], bits);
        } else {
            if (iou > best) { best = iou; bi = g; }
            rescue = rescue | (iou == gc.z);   // exact-equality rescue
        }
    }

    if (PASS == 0) {
        __syncthreads();
        if (t < MGT && s_max[t] > 0) atomicMax(&gbest_bits[t], s_max[t]);
        return;
    }

    const float label = rescue ? 1.0f
                      : (best >= 0.5f ? 1.0f : (best >= 0.35f ? -1.0f : 0.0f));

    // ---- encode deltas (deltas 0..5 + match/label shared by both yaws)
    const float ax = s_xc[lx], ay = s_yc[ly];
    const float gx = s_gt[bi][0], gy = s_gt[bi][1], gz = s_gt[bi][2];
    const float gw = s_gt[bi][3], gl = s_gt[bi][4], gh = s_gt[bi][5];
    const float gyaw = s_gt[bi][6];

    const float diag = sqrtf(w*w + l*l);
    float d7[7];
    d7[0] = (gx - ax) / diag;
    d7[1] = (gy - ay) / diag;
    d7[2] = (gz - zc) / h;
    d7[3] = logf(gw / w);
    d7[4] = logf(gl / l);
    d7[5] = logf(gh / h);
    float r0 = fmodf(gyaw - s_cls[4], PI_F);  if (r0 < 0.0f) r0 += PI_F;
    float r1 = fmodf(gyaw - s_cls[5], PI_F);  if (r1 < 0.0f) r1 += PI_F;

    const int x = x0 + lx, y = y0 + ly;
    const size_t i0 = ((size_t)(x*NYg + y))*6 + c;   // yaw 0 anchor index
    const size_t i1 = i0 + 3;                        // yaw 1 anchor index

    d7[6] = r0;
    #pragma unroll
    for (int k = 0; k < 7; ++k) out[i0*7 + k] = d7[k];
    d7[6] = r1;
    #pragma unroll
    for (int k = 0; k < 7; ++k) out[i1*7 + k] = d7[k];

    out[(size_t)NANCH*7 + i0] = (float)bi;
    out[(size_t)NANCH*7 + i1] = (float)bi;
    out[(size_t)NANCH*8 + i0] = label;
    out[(size_t)NANCH*8 + i1] = label;
}

extern "C" void kernel_launch(void* const* d_in, const int* in_sizes, int n_in,
                              void* d_out, int out_size, void* d_ws, size_t ws_size,
                              hipStream_t stream)
{
    const float* gt   = (const float*)d_in[0];
    const float* anch = (const float*)d_in[1];
    if (in_sizes[0] != MGT*7) { gt = (const float*)d_in[1]; anch = (const float*)d_in[0]; }

    float* out   = (float*)d_out;
    int*   gbest = (int*)d_ws;   // 64 ints of iou bits, rebuilt every call

    hipMemsetAsync(gbest, 0, MGT*sizeof(int), stream);  // graph-capturable
    const dim3 grid(NXg/TX, NYg/TY, 3);
    tile_kernel<0><<<grid, 128, 0, stream>>>(gt, anch, gbest, out);
    tile_kernel<1><<<grid, 128, 0, stream>>>(gt, anch, gbest, out);
}